// Round 5
// baseline (1436.265 us; speedup 1.0000x reference)
//
#include <hip/hip_runtime.h>

typedef unsigned short u16;
typedef unsigned int u32;
typedef unsigned long long u64;
typedef __attribute__((ext_vector_type(8))) short short8;
typedef __attribute__((ext_vector_type(4))) float floatx4;

#define E_ 1024
#define B_ 256
#define M_ 196
#define H_ 8
#define DH_ 128
#define MID_ 64
#define NKROW 50176   // B_*M_

__device__ __forceinline__ u16 f2bf(float f){
  union { float f; u32 u; } v; v.f = f;
  return (u16)((v.u + (((v.u >> 16) & 1u) + 0x7fffu)) >> 16);
}
__device__ __forceinline__ float bf2f(u16 h){
  union { u32 u; float f; } v; v.u = ((u32)h) << 16;
  return v.f;
}
__device__ __forceinline__ u32 pack_bf2(float a, float b){
  u32 ua = __float_as_uint(a) + 0x8000u;
  u32 ub = __float_as_uint(b) + 0x8000u;
  return __builtin_amdgcn_perm(ub, ua, 0x07060302);
}
__device__ __forceinline__ float celu_f(float x){
  float xn = 1.3f * (__expf(x * 0.76923076923f) - 1.0f);
  return x > 0.f ? x : xn;
}

// ---------------------------------------------------------------------------
// Kernel X: in-place fp32 -> bf16, coalesced. Row r -> bf16 at u16-offset
// r*2048 (row stride 2048 u16 = 4 KB, front half used).
// ---------------------------------------------------------------------------
__global__ __launch_bounds__(256) void xconv_kernel(
    float* __restrict__ key, float* __restrict__ value2,
    float* __restrict__ query, float* __restrict__ value1)
{
  int gr = blockIdx.x * 8 + (threadIdx.x >> 5);
  int i  = threadIdx.x & 31;
  float* X; int r;
  if (gr < NKROW)               { X = key;    r = gr; }
  else if (gr < 2*NKROW)        { X = value2; r = gr - NKROW; }
  else if (gr < 2*NKROW + B_)   { X = query;  r = gr - 2*NKROW; }
  else                          { X = value1; r = gr - 2*NKROW - B_; }
  const float4* src = (const float4*)(X + (size_t)r * E_);
  float4 v[8];
  #pragma unroll
  for (int j = 0; j < 8; j++) v[j] = src[j * 32 + i];
  __syncthreads();
  uint2* dst = (uint2*)((u16*)X + (size_t)r * 2048);
  #pragma unroll
  for (int j = 0; j < 8; j++){
    uint2 o;
    o.x = pack_bf2(v[j].x, v[j].y);
    o.y = pack_bf2(v[j].z, v[j].w);
    dst[j * 32 + i] = o;
  }
}

// ---------------------------------------------------------------------------
// Kernel 0: convert+transpose the 4 weight matrices to bf16 [col][k].
// ---------------------------------------------------------------------------
__global__ __launch_bounds__(256) void wconv_kernel(
    const float* __restrict__ Wq, const float* __restrict__ Wk,
    const float* __restrict__ Wv1, const float* __restrict__ Wv2,
    u16* __restrict__ Wt)
{
  __shared__ u16 tile[64][72];
  const float* W = (blockIdx.z == 0) ? Wq : (blockIdx.z == 1) ? Wk
                 : (blockIdx.z == 2) ? Wv1 : Wv2;
  u16* out = Wt + (size_t)blockIdx.z * (E_ * E_);
  int k0 = blockIdx.x * 64, c0 = blockIdx.y * 64;
  int tx = threadIdx.x & 63, ty = threadIdx.x >> 6;
  #pragma unroll
  for (int i = 0; i < 16; i++){
    int k = ty * 16 + i;
    tile[k][tx] = f2bf(W[(size_t)(k0 + k) * E_ + c0 + tx]);
  }
  __syncthreads();
  #pragma unroll
  for (int i = 0; i < 16; i++){
    int c = ty * 16 + i;
    out[(size_t)(c0 + c) * E_ + k0 + tx] = tile[tx][c];
  }
}

// ---------------------------------------------------------------------------
// Kernel 1: fused GEMM + bias + celu + group-norm — BARRIER-FREE, LDS-FREE.
// Block = 128 rows x 128 cols (one head-group of columns), 4 waves, each
// wave 32 rows x 128 cols: 2x8 frags of 16x16x32 bf16 (64 AGPR). A/B frags
// load DIRECTLY from global each kt: every frag load touches 16 complete
// 64-B lines (100% utilization); B panel (256 KB) is L2-resident, A (104 MB
// bf16 total) is L3-resident after the first col pass. No __syncthreads =>
// no vmcnt(0) drains: the compiler interleaves MFMA with loads using
// fine-grained vmcnt (the AITER pattern, HIP-expressible only without LDS).
// ~150 regs => 3 waves/SIMD, 12 independent waves/CU for latency hiding.
// Groupnorm: the wave owns all 128 cols of the group => in-wave reduction.
// ---------------------------------------------------------------------------
__global__ __launch_bounds__(256) void proj_kernel(
    const u16* __restrict__ xq_, const u16* __restrict__ xk_,
    const u16* __restrict__ xv1_, const u16* __restrict__ xv2_,
    const float* __restrict__ bq, const float* __restrict__ gqw, const float* __restrict__ gqb,
    const float* __restrict__ bk, const float* __restrict__ gkw, const float* __restrict__ gkb,
    const float* __restrict__ bv1, const float* __restrict__ gv1w, const float* __restrict__ gv1b,
    const float* __restrict__ bv2, const float* __restrict__ gv2w, const float* __restrict__ gv2b,
    const u16* __restrict__ Wt,
    u16* __restrict__ qout, u16* __restrict__ khead,
    u16* __restrict__ v1out, u16* __restrict__ v2head)
{
  const int tid = threadIdx.x;
  const int w = tid >> 6, lane = tid & 63, qd = lane >> 4, lr = lane & 15;

  const int mtb = blockIdx.x;
  const u16* X; const float *bias, *gw, *gb; u16* outp; int row0, matsel, hm;
  if (mtb < 392)      { X = xk_;  bias = bk;  gw = gkw;  gb = gkb;  outp = khead;  row0 = mtb*128;        matsel = 1; hm = 1; }
  else if (mtb < 784) { X = xv2_; bias = bv2; gw = gv2w; gb = gv2b; outp = v2head; row0 = (mtb-392)*128;  matsel = 3; hm = 1; }
  else if (mtb < 786) { X = xq_;  bias = bq;  gw = gqw;  gb = gqb;  outp = qout;   row0 = (mtb-784)*128;  matsel = 0; hm = 0; }
  else                { X = xv1_; bias = bv1; gw = gv1w; gb = gv1b; outp = v1out;  row0 = (mtb-786)*128;  matsel = 2; hm = 0; }
  const int head = blockIdx.y, col0 = head * DH_;

  // frag source pointers (per-lane): A row = row0 + w*32 + m2*16 + lr,
  // k-chunk = qd*8; in-place A rows have stride 2048 u16.
  const u16* ap0 = X + (size_t)(row0 + w*32 + lr) * 2048 + qd * 8;
  const u16* ap1 = ap0 + (size_t)16 * 2048;
  const u16* wbase = Wt + (size_t)matsel * (E_*E_);
  const u16* bp = wbase + (size_t)(col0 + lr) * E_ + qd * 8;   // + nt*16*E_

  floatx4 acc[2][8];
  #pragma unroll
  for (int i = 0; i < 2; i++)
    #pragma unroll
    for (int j = 0; j < 8; j++){
      floatx4 z = {0.f, 0.f, 0.f, 0.f};
      acc[i][j] = z;
    }

  #pragma unroll 2
  for (int kt = 0; kt < 32; kt++){
    const int ko = kt * 32;
    short8 a0 = *(const short8*)(ap0 + ko);
    short8 a1 = *(const short8*)(ap1 + ko);
    short8 bf[8];
    #pragma unroll
    for (int nt = 0; nt < 8; nt++)
      bf[nt] = *(const short8*)(bp + (size_t)nt * 16 * E_ + ko);
    #pragma unroll
    for (int nt = 0; nt < 8; nt++){
      acc[0][nt] = __builtin_amdgcn_mfma_f32_16x16x32_bf16(a0, bf[nt], acc[0][nt], 0, 0, 0);
      acc[1][nt] = __builtin_amdgcn_mfma_f32_16x16x32_bf16(a1, bf[nt], acc[1][nt], 0, 0, 0);
    }
  }

  // Epilogue: bias + celu, in-wave groupnorm over the 128-col group, store.
  float biasv[8], gwv[8], gbv[8];
  #pragma unroll
  for (int nt = 0; nt < 8; nt++){
    int c = col0 + nt*16 + lr;
    biasv[nt] = bias[c]; gwv[nt] = gw[c]; gbv[nt] = gb[c];
  }
  #pragma unroll
  for (int m2 = 0; m2 < 2; m2++){
    #pragma unroll
    for (int r = 0; r < 4; r++){
      float s = 0.f, s2 = 0.f;
      #pragma unroll
      for (int nt = 0; nt < 8; nt++){
        float x = celu_f(acc[m2][nt][r] + biasv[nt]);
        acc[m2][nt][r] = x;
        s += x; s2 += x * x;
      }
      #pragma unroll
      for (int off = 1; off < 16; off <<= 1){
        s  += __shfl_xor(s,  off, 64);
        s2 += __shfl_xor(s2, off, 64);
      }
      float mean = s * 0.0078125f;
      float var  = s2 * 0.0078125f - mean * mean;
      float rstd = rsqrtf(var + 1e-5f);
      u32 rg = row0 + w*32 + m2*16 + qd*4 + r;
      size_t base;
      if (hm){
        u32 bi = (u32)(((u64)rg * 171197ull) >> 25);   // exact rg/196 (rg < 186413)
        u32 m  = rg - bi * 196u;
        base = ((size_t)(bi*H_ + head)*M_ + m) * DH_;
      } else {
        base = (size_t)rg * E_ + head * DH_;
      }
      #pragma unroll
      for (int nt = 0; nt < 8; nt++)
        outp[base + nt*16 + lr] = f2bf((acc[m2][nt][r] - mean) * rstd * gwv[nt] + gbv[nt]);
    }
  }
}

// ---------------------------------------------------------------------------
// Kernel 2: per-(b,h) attention. hidden = relu(khead @ (diag(q)Wb) + bb) via
// MFMA (never materialized). v2-pool loads PREFETCHED into registers before
// the softmax reduction barriers so their HBM latency hides behind them.
// ---------------------------------------------------------------------------
__global__ __launch_bounds__(256) void attn_kernel(
    const u16* __restrict__ qproj, const u16* __restrict__ khead,
    const u16* __restrict__ v1proj, const u16* __restrict__ v2head,
    const int* __restrict__ mask,
    const float* __restrict__ Wb, const float* __restrict__ bb,
    const float* __restrict__ Ws, const float* __restrict__ bs,
    const float* __restrict__ Wc, const float* __restrict__ bc,
    float* __restrict__ outp)
{
  __shared__ u16 wbt[64 * 136];      // B' = diag(q)*Wb, [n][k], stride 136
  __shared__ float qv[128];
  __shared__ float mrow[208];
  __shared__ float logitv[208];
  __shared__ float hsum_l[4][64];
  __shared__ float wexpv[208];
  __shared__ float poolv[64];
  __shared__ float v2acc[4][128];
  __shared__ float wc2[2][128];
  __shared__ float red[8];

  const int tid = threadIdx.x;
  const int w = tid >> 6, lane = tid & 63, qd = lane >> 4, lr = lane & 15;
  const int b = blockIdx.y, h = blockIdx.x;

  const u16* kbase  = khead  + (size_t)(b*H_ + h) * (M_*DH_);
  const u16* v2base = v2head + (size_t)(b*H_ + h) * (M_*DH_);

  if (tid < 128) qv[tid] = bf2f(qproj[(size_t)b * E_ + h * DH_ + tid]);
  if (tid < 208) mrow[tid] = (tid < M_) ? (float)mask[b * M_ + tid] : 0.f;
  __syncthreads();

  {
    int n = tid & 63, kb = (tid >> 6) * 32;
    #pragma unroll
    for (int kk = 0; kk < 32; kk++)
      wbt[n * 136 + kb + kk] = f2bf(qv[kb + kk] * Wb[(kb + kk) * MID_ + n]);
  }
  __syncthreads();

  float wsv[4], bbv[4];
  #pragma unroll
  for (int nt = 0; nt < 4; nt++){ wsv[nt] = Ws[nt * 16 + lr]; bbv[nt] = bb[nt * 16 + lr]; }
  const float bsv = bs[0];
  float hs[4] = {0, 0, 0, 0};

  #pragma unroll
  for (int it = 0; it < 4; it++){
    int mt = w + it * 4;
    if (mt >= 13) continue;
    int mrow_g = mt * 16 + lr;
    int mcl = (mrow_g < M_) ? mrow_g : (M_ - 1);
    const u16* arow = kbase + (size_t)mcl * DH_;
    floatx4 hacc[4];
    #pragma unroll
    for (int nt = 0; nt < 4; nt++){ floatx4 z = {0.f, 0.f, 0.f, 0.f}; hacc[nt] = z; }
    #pragma unroll
    for (int kc = 0; kc < 4; kc++){
      short8 afr = *(const short8*)(arow + kc * 32 + qd * 8);
      #pragma unroll
      for (int nt = 0; nt < 4; nt++){
        short8 bfr = *(const short8*)&wbt[(nt * 16 + lr) * 136 + kc * 32 + qd * 8];
        hacc[nt] = __builtin_amdgcn_mfma_f32_16x16x32_bf16(afr, bfr, hacc[nt], 0, 0, 0);
      }
    }
    float lp[4] = {0, 0, 0, 0};
    #pragma unroll
    for (int nt = 0; nt < 4; nt++){
      #pragma unroll
      for (int r = 0; r < 4; r++){
        float hv = hacc[nt][r] + bbv[nt];
        hv = fmaxf(hv, 0.f);
        lp[r] += hv * wsv[nt];
        hs[nt] += mrow[mt * 16 + qd * 4 + r] * hv;
      }
    }
    #pragma unroll
    for (int r = 0; r < 4; r++){
      float a = lp[r];
      #pragma unroll
      for (int off = 1; off < 16; off <<= 1) a += __shfl_xor(a, off, 64);
      if (lr == 0) logitv[mt * 16 + qd * 4 + r] = a + bsv;
    }
  }
  #pragma unroll
  for (int nt = 0; nt < 4; nt++){
    hs[nt] += __shfl_xor(hs[nt], 16, 64);
    hs[nt] += __shfl_xor(hs[nt], 32, 64);
  }
  if (lane < 16){
    #pragma unroll
    for (int nt = 0; nt < 4; nt++) hsum_l[w][nt * 16 + lane] = hs[nt];
  }

  // ---- prefetch all v2 pooling data into registers (latency hidden behind
  // the softmax reduction phases below) ----
  uint4 v2r[13];
  #pragma unroll
  for (int it = 0; it < 13; it++){
    int m = it * 16 + w * 4 + qd;
    int msafe = (m < M_) ? m : 0;
    v2r[it] = *(const uint4*)(v2base + (size_t)msafe * DH_ + lr * 8);
  }
  __syncthreads();

  if (w == 0){
    float s = 0.f;
    for (int m = lane; m < M_; m += 64) s += mrow[m];
    #pragma unroll
    for (int off = 1; off < 64; off <<= 1) s += __shfl_xor(s, off, 64);
    if (lane == 0) red[0] = s;
  } else if (w == 1){
    float mx = -1e30f;
    for (int m = lane; m < M_; m += 64) if (mrow[m] > 0.5f) mx = fmaxf(mx, logitv[m]);
    #pragma unroll
    for (int off = 1; off < 64; off <<= 1) mx = fmaxf(mx, __shfl_xor(mx, off, 64));
    if (lane == 0) red[1] = mx;
  } else if (w == 2){
    poolv[lane & 63] = hsum_l[0][lane & 63] + hsum_l[1][lane & 63]
                     + hsum_l[2][lane & 63] + hsum_l[3][lane & 63];
  }
  __syncthreads();
  const float cnt = red[0], mx = red[1];
  if (tid < 208)
    wexpv[tid] = (tid < M_ && mrow[tid] > 0.5f) ? __expf(logitv[tid] - mx) : 0.f;
  __syncthreads();
  if (w == 0){
    float s = 0.f;
    for (int m = lane; m < M_; m += 64) s += wexpv[m];
    #pragma unroll
    for (int off = 1; off < 64; off <<= 1) s += __shfl_xor(s, off, 64);
    if (lane == 0) red[2] = s;
  } else if (w == 1){
    poolv[lane & 63] = poolv[lane & 63] / cnt;
  }
  __syncthreads();
  const float S = red[2];

  // v2 pooling FMA on prefetched registers
  {
    float ac[8] = {0, 0, 0, 0, 0, 0, 0, 0};
    #pragma unroll
    for (int it = 0; it < 13; it++){
      int m = it * 16 + w * 4 + qd;
      float we = (m < M_) ? wexpv[m] : 0.f;
      uint4 u = v2r[it];
      ac[0] += we * bf2f((u16)(u.x & 0xffff));
      ac[1] += we * bf2f((u16)(u.x >> 16));
      ac[2] += we * bf2f((u16)(u.y & 0xffff));
      ac[3] += we * bf2f((u16)(u.y >> 16));
      ac[4] += we * bf2f((u16)(u.z & 0xffff));
      ac[5] += we * bf2f((u16)(u.z >> 16));
      ac[6] += we * bf2f((u16)(u.w & 0xffff));
      ac[7] += we * bf2f((u16)(u.w >> 16));
    }
    #pragma unroll
    for (int j = 0; j < 8; j++){
      ac[j] += __shfl_xor(ac[j], 16, 64);
      ac[j] += __shfl_xor(ac[j], 32, 64);
    }
    if (qd == 0){
      #pragma unroll
      for (int j = 0; j < 8; j++) v2acc[w][lr * 8 + j] = ac[j];
    }
  }

  // channel gate gemv in parallel with v2acc write
  {
    int d = tid & 127, jh = tid >> 7;
    float a = 0.f;
    #pragma unroll 8
    for (int j = jh * 32; j < jh * 32 + 32; j++) a += poolv[j] * Wc[j * DH_ + d];
    wc2[jh][d] = a;
  }
  __syncthreads();

  if (tid < 128){
    float a = wc2[0][tid] + wc2[1][tid];
    float acv = 1.f / (1.f + __expf(-(a + bc[tid])));
    float vp = (v2acc[0][tid] + v2acc[1][tid] + v2acc[2][tid] + v2acc[3][tid]) / S;
    float o = bf2f(v1proj[(size_t)b * E_ + h * DH_ + tid]) * vp * acv;
    outp[(size_t)b * E_ + h * DH_ + tid] = o;
  }
}

// ---------------------------------------------------------------------------
extern "C" void kernel_launch(void* const* d_in, const int* in_sizes, int n_in,
                              void* d_out, int out_size, void* d_ws, size_t ws_size,
                              hipStream_t stream)
{
  float* query  = (float*)d_in[0];
  float* key    = (float*)d_in[1];
  const int* mask = (const int*)d_in[2];
  float* value1 = (float*)d_in[3];
  float* value2 = (float*)d_in[4];
  const float* Wq  = (const float*)d_in[5];
  const float* bq  = (const float*)d_in[6];
  const float* gqw = (const float*)d_in[7];
  const float* gqb = (const float*)d_in[8];
  const float* Wk  = (const float*)d_in[9];
  const float* bk  = (const float*)d_in[10];
  const float* gkw = (const float*)d_in[11];
  const float* gkb = (const float*)d_in[12];
  const float* Wv1 = (const float*)d_in[13];
  const float* bv1 = (const float*)d_in[14];
  const float* gv1w= (const float*)d_in[15];
  const float* gv1b= (const float*)d_in[16];
  const float* Wv2 = (const float*)d_in[17];
  const float* bv2 = (const float*)d_in[18];
  const float* gv2w= (const float*)d_in[19];
  const float* gv2b= (const float*)d_in[20];
  const float* Wb  = (const float*)d_in[21];
  const float* bb  = (const float*)d_in[22];
  const float* Ws  = (const float*)d_in[23];
  const float* bs  = (const float*)d_in[24];
  const float* Wc  = (const float*)d_in[25];
  const float* bc  = (const float*)d_in[26];

  const size_t NHD = (size_t)B_ * H_ * M_ * DH_;   // 51,380,224
  u16* khead  = (u16*)d_ws;
  u16* v2head = khead  + NHD;
  u16* qout   = v2head + NHD;
  u16* v1out  = qout   + (size_t)B_ * E_;
  u16* Wt     = v1out  + (size_t)B_ * E_;          // 4 * 1024*1024 bf16

  xconv_kernel<<<(2*NKROW + 2*B_)/8, 256, 0, stream>>>(key, value2, query, value1);

  dim3 g0(16, 16, 4);
  wconv_kernel<<<g0, 256, 0, stream>>>(Wq, Wk, Wv1, Wv2, Wt);

  dim3 g1(788, 8);   // x = row panel (fast: streams A, B panel L2-resident)
  proj_kernel<<<g1, 256, 0, stream>>>(
      (const u16*)query, (const u16*)key, (const u16*)value1, (const u16*)value2,
      bq, gqw, gqb, bk, gkw, gkb, bv1, gv1w, gv1b, bv2, gv2w, gv2b,
      Wt, qout, khead, v1out, v2head);

  dim3 g2(H_, B_);
  attn_kernel<<<g2, 256, 0, stream>>>(qout, khead, v1out, v2head, mask,
      Wb, bb, Ws, bs, Wc, bc, (float*)d_out);
}